// Round 5
// baseline (150.530 us; speedup 1.0000x reference)
//
#include <hip/hip_runtime.h>

#define BB 8
#define NS 5
#define NQ 75
#define NG 4
#define NF 49
#define CDIM 64

#define SUPROWS (BB * NG * NS * 64)     // 10240 rows
#define QRYROWS (BB * NQ * NG * 64)     // 153600 rows
#define TOTROWS (SUPROWS + QRYROWS)     // 163840 rows x 64 bf16
#define NOUT (BB * NQ * NS)             // 3000

typedef __attribute__((ext_vector_type(8))) short bf16x8;
typedef __attribute__((ext_vector_type(16))) float f32x16;

__device__ __forceinline__ float multi_gauss(float d2) {
    d2 = fmaxf(d2, 0.f);
    float e  = __expf(-0.125f * d2);
    float e2 = e * e, e4 = e2 * e2, e8 = e4 * e4, e16 = e8 * e8;
    return e + e2 + e4 + e8 + e16;
}

// scaled-domain: arg = -0.125*log2(e)*d2 (<=0); K = t+t^2+t^4+t^8+t^16
__device__ __forceinline__ float multi_gauss2(float arg) {
    float e  = __builtin_amdgcn_exp2f(fminf(arg, 0.f));
    float e2 = e * e, e4 = e2 * e2, e8 = e4 * e4, e16 = e8 * e8;
    return ((e + e2) + (e4 + e8)) + e16;
}

__device__ __forceinline__ unsigned short f2bf(float x) {
    union { float f; unsigned u; } c; c.f = x;
    unsigned r = c.u + 0x7FFFu + ((c.u >> 16) & 1u);   // RNE
    return (unsigned short)(r >> 16);
}

__device__ __forceinline__ float wred(float x) {
    for (int o = 32; o; o >>= 1) x += __shfl_down(x, o, 64);
    return x;
}

// ---------------------------------------------------------------------------
// Kernel 1: prep — fp32 -> bf16 rows (zero-padded to 64 feats) + fp32 ssq;
// also zeros the 3000-float output. 16 threads/row, float4 each. 10240 blocks.
// ---------------------------------------------------------------------------
__global__ __launch_bounds__(256) void prep(
    const float* __restrict__ sup, const float* __restrict__ qry,
    unsigned short* __restrict__ whi, float* __restrict__ wssq,
    float* __restrict__ out)
{
    int u = blockIdx.x * 256 + threadIdx.x;
    if (u < NOUT) out[u] = 0.f;

    int row = u >> 4;
    int c = (u & 15) * 4;

    const float* src = nullptr;
    if (row < SUPROWS) {
        int i = row & 63, t6 = row >> 6;
        int s = t6 % NS, bg = t6 / NS;
        int g = bg & 3, b = bg >> 2;
        if (i < NF) src = sup + ((size_t)(((b * NS + s) * NG + g) * NF + i)) * CDIM + c;
    } else {
        int r2 = row - SUPROWS;
        int j = r2 & 63, t6 = r2 >> 6;
        int g = t6 & 3, v = (t6 >> 2) % NQ, b = t6 / (NQ * NG);
        if (j < NF) src = qry + ((size_t)(((b * NQ + v) * NG + g) * NF + j)) * CDIM + c;
    }
    float4 x = make_float4(0.f, 0.f, 0.f, 0.f);
    if (src) x = *(const float4*)src;
    ushort4 h4;
    h4.x = f2bf(x.x); h4.y = f2bf(x.y); h4.z = f2bf(x.z); h4.w = f2bf(x.w);
    ((ushort4*)whi)[u] = h4;

    float v2 = x.x * x.x + x.y * x.y + x.z * x.z + x.w * x.w;
    v2 += __shfl_down(v2, 8, 64);
    v2 += __shfl_down(v2, 4, 64);
    v2 += __shfl_down(v2, 2, 64);
    v2 += __shfl_down(v2, 1, 64);
    if ((u & 15) == 0) wssq[row] = v2;
}

// ---------------------------------------------------------------------------
// Kernel 2: kss — 64x64 Kss tiles via MFMA, exact-diagonal fixup K(0)=5.
// 160 blocks = (b*NG+g)*NS + s; rows [64k, 64k+64) of ws. Output fp32.
// ---------------------------------------------------------------------------
__global__ __launch_bounds__(256) void kss(
    const unsigned short* __restrict__ whi, const float* __restrict__ wssq,
    float* __restrict__ wkss)
{
    int k = blockIdx.x;
    int row0 = k * 64;
    int t = threadIdx.x;
    int w = t >> 6, lane = t & 63, lrow = lane & 31, lhalf = lane >> 5;
    int mt = w >> 1, ntile = w & 1;

    const bf16x8* W = (const bf16x8*)whi;
    f32x16 acc;
#pragma unroll
    for (int q = 0; q < 16; ++q) acc[q] = 0.f;
#pragma unroll
    for (int kc = 0; kc < 4; ++kc) {
        int ko = kc * 2 + lhalf;
        bf16x8 a  = W[(row0 + mt * 32 + lrow) * 8 + ko];
        bf16x8 bf = W[(row0 + ntile * 32 + lrow) * 8 + ko];
        acc = __builtin_amdgcn_mfma_f32_32x32x16_bf16(a, bf, acc, 0, 0, 0);
    }
    int cj = ntile * 32 + lrow;
    float sqj = wssq[row0 + cj];
#pragma unroll
    for (int reg = 0; reg < 16; ++reg) {
        int ri = mt * 32 + (reg & 3) + 8 * (reg >> 2) + 4 * lhalf;
        float kv = (ri == cj) ? 5.0f
                 : multi_gauss(wssq[row0 + ri] + sqj - 2.f * acc[reg]);
        wkss[(size_t)k * 4096 + ri * 64 + cj] = kv;
    }
}

// ---------------------------------------------------------------------------
// Kernel 3: MFMA cross + qq + ss-forms. One block per (b,v,g,half): 4800 blocks.
// ---------------------------------------------------------------------------
__global__ __launch_bounds__(256, 5) void mmd_cross(
    const unsigned short* __restrict__ whi, const float* __restrict__ wssq,
    const float* __restrict__ wkss,
    const float* __restrict__ beta, const float* __restrict__ gamma,
    float* __restrict__ out)
{
    int blk = blockIdx.x;
    int h = blk & 1;
    int g = (blk >> 1) & 3;
    int v = (blk >> 3) % NQ;
    int b = blk / (NQ * NG * 2);

    __shared__ float sbeta[NS][64], sgam[NS][64];
    __shared__ float ssq[384];
    __shared__ float red_sq[NS], red_qq[NS], red_ss[NS];

    int t = threadIdx.x;
    int w = t >> 6, lane = t & 63, lrow = lane & 31, lhalf = lane >> 5;
    int qc = h * 32;

    int srow0 = (b * NG + g) * (NS * 64);
    int qrow0 = SUPROWS + ((b * NQ + v) * NG + g) * 64;

    for (int u = t; u < 384; u += 256)
        ssq[u] = (u < 320) ? wssq[srow0 + u] : wssq[qrow0 + (u - 320)];
    for (int u = t; u < NS * 64; u += 256) {
        int s = u >> 6, i = u & 63;
        float bvv = 0.f, gvv = 0.f;
        if (i < NF) {
            size_t base = (size_t)(((b * NQ + v) * NS + s) * NG + g) * NF + i;
            bvv = beta[base]; gvv = gamma[base];
        }
        sbeta[s][i] = bvv; sgam[s][i] = gvv;
    }
    if (t < NS) { red_sq[t] = 0.f; red_qq[t] = 0.f; red_ss[t] = 0.f; }

    const bf16x8* W = (const bf16x8*)whi;

    f32x16 acc[3];
#pragma unroll
    for (int mi = 0; mi < 3; ++mi)
#pragma unroll
        for (int q = 0; q < 16; ++q) acc[mi][q] = 0.f;

    int a2row = (w < 2) ? (srow0 + (8 + w) * 32 + lrow)
                        : (qrow0 + (w - 2) * 32 + lrow);
#pragma unroll
    for (int kc = 0; kc < 4; ++kc) {
        int ko = kc * 2 + lhalf;
        bf16x8 bh = W[(qrow0 + qc + lrow) * 8 + ko];
        bf16x8 a0 = W[(srow0 + w * 32 + lrow) * 8 + ko];
        bf16x8 a1 = W[(srow0 + (w + 4) * 32 + lrow) * 8 + ko];
        bf16x8 a2 = W[a2row * 8 + ko];
        acc[0] = __builtin_amdgcn_mfma_f32_32x32x16_bf16(a0, bh, acc[0], 0, 0, 0);
        acc[1] = __builtin_amdgcn_mfma_f32_32x32x16_bf16(a1, bh, acc[1], 0, 0, 0);
        acc[2] = __builtin_amdgcn_mfma_f32_32x32x16_bf16(a2, bh, acc[2], 0, 0, 0);
    }
    __syncthreads();   // staging + red inits visible

    const float c2  = -0.18033688f;   // -0.125 * log2(e)
    const float k2c =  0.36067376f;   // -2 * c2
    float qsq = ssq[320 + qc + lrow];
    float c2q = c2 * qsq;

#pragma unroll
    for (int mi = 0; mi < 3; ++mi) {
        int mt = (mi < 2) ? (w + 4 * mi) : ((w < 2) ? (8 + w) : -1);
        if (mt >= 0) {                 // cross tile: s = mt>>1
            int s = mt >> 1;
            int ioff = (mt & 1) * 32;
            float tsum = 0.f;
#pragma unroll
            for (int grp = 0; grp < 4; ++grp) {
                int rbase = grp * 8 + 4 * lhalf;
                float4 sqv = *(const float4*)&ssq[mt * 32 + rbase];
                float4 bvv = *(const float4*)&sbeta[s][ioff + rbase];
#pragma unroll
                for (int q = 0; q < 4; ++q) {
                    float sq = (q == 0) ? sqv.x : (q == 1) ? sqv.y : (q == 2) ? sqv.z : sqv.w;
                    float bv = (q == 0) ? bvv.x : (q == 1) ? bvv.y : (q == 2) ? bvv.z : bvv.w;
                    float arg = fmaf(k2c, acc[mi][grp * 4 + q], fmaf(c2, sq, c2q));
                    tsum = fmaf(bv, multi_gauss2(arg), tsum);
                }
            }
            tsum *= sgam[s][qc + lrow];
            tsum = wred(tsum);
            if (lane == 0) atomicAdd(&red_sq[s], tsum);
        } else {                       // qq tile
            int qoff = (w - 2) * 32;
            float qs[NS] = {0.f, 0.f, 0.f, 0.f, 0.f};
#pragma unroll
            for (int grp = 0; grp < 4; ++grp) {
                int rbase = grp * 8 + 4 * lhalf;
                float4 sqv = *(const float4*)&ssq[320 + qoff + rbase];
                float kvv[4];
#pragma unroll
                for (int q = 0; q < 4; ++q) {
                    float sq = (q == 0) ? sqv.x : (q == 1) ? sqv.y : (q == 2) ? sqv.z : sqv.w;
                    int row = qoff + rbase + q;
                    float arg = fmaf(k2c, acc[mi][grp * 4 + q], fmaf(c2, sq, c2q));
                    kvv[q] = (row == qc + lrow) ? 5.0f : multi_gauss2(arg);
                }
#pragma unroll
                for (int s = 0; s < NS; ++s) {
                    float4 gi = *(const float4*)&sgam[s][qoff + rbase];
                    qs[s] = fmaf(gi.x, kvv[0], qs[s]);
                    qs[s] = fmaf(gi.y, kvv[1], qs[s]);
                    qs[s] = fmaf(gi.z, kvv[2], qs[s]);
                    qs[s] = fmaf(gi.w, kvv[3], qs[s]);
                }
            }
#pragma unroll
            for (int s = 0; s < NS; ++s) {
                float r = wred(qs[s] * sgam[s][qc + lrow]);
                if (lane == 0) atomicAdd(&red_qq[s], r);
            }
        }
    }

    // ss quadratic forms: this block handles columns j in [qc, qc+32).
    // thread: j = qc + (t&31)  (coalesced), rows i in [ (t>>5)*8, +8 ).
    {
        int jj = qc + (t & 31);
        int ig = (t >> 5) * 8;
        const float* Kb = wkss + (size_t)((b * NG + g) * NS) * 4096 + jj;
#pragma unroll
        for (int s = 0; s < NS; ++s) {
            const float* Kc = Kb + (size_t)s * 4096;
            float u2 = 0.f;
#pragma unroll
            for (int r = 0; r < 8; ++r)
                u2 = fmaf(sbeta[s][ig + r], Kc[(ig + r) * 64], u2);
            u2 *= sbeta[s][jj];
            u2 = wred(u2);
            if (lane == 0) atomicAdd(&red_ss[s], u2);
        }
    }

    __syncthreads();
    if (t < NS)
        atomicAdd(&out[((size_t)b * NQ + v) * NS + t],
                  0.25f * (red_ss[t] + red_qq[t] - 2.f * red_sq[t]));
}

extern "C" void kernel_launch(void* const* d_in, const int* in_sizes, int n_in,
                              void* d_out, int out_size, void* d_ws, size_t ws_size,
                              hipStream_t stream) {
    const float* sup   = (const float*)d_in[0];
    const float* qry   = (const float*)d_in[1];
    const float* beta  = (const float*)d_in[2];
    const float* gamma = (const float*)d_in[3];
    float* out = (float*)d_out;

    unsigned short* whi = (unsigned short*)d_ws;                 // 21 MB
    float* wssq = (float*)(whi + (size_t)TOTROWS * 64);          // 0.66 MB
    float* wkss = wssq + TOTROWS;                                // 2.62 MB

    prep<<<(TOTROWS * 16) / 256, 256, 0, stream>>>(sup, qry, whi, wssq, out);
    kss<<<BB * NG * NS, 256, 0, stream>>>(whi, wssq, wkss);
    mmd_cross<<<BB * NQ * NG * 2, 256, 0, stream>>>(whi, wssq, wkss, beta, gamma, out);
}

// Round 6
// 132.888 us; speedup vs baseline: 1.1328x; 1.1328x over previous
//
#include <hip/hip_runtime.h>

#define BB 8
#define NS 5
#define NQ 75
#define NG 4
#define NF 49
#define CDIM 64

#define SUPROWS (BB * NG * NS * 64)     // 10240 rows
#define QRYROWS (BB * NQ * NG * 64)     // 153600 rows
#define TOTROWS (SUPROWS + QRYROWS)     // 163840 rows x 64 bf16
#define NOUT (BB * NQ * NS)             // 3000
#define NCROSS (BB * NQ * NG * 2)       // 4800 cross blocks
#define NFORM (BB * NG * NS)            // 160 forms blocks

typedef __attribute__((ext_vector_type(8))) short bf16x8;
typedef __attribute__((ext_vector_type(16))) float f32x16;

__device__ __forceinline__ float multi_gauss(float d2) {
    d2 = fmaxf(d2, 0.f);
    float e  = __expf(-0.125f * d2);
    float e2 = e * e, e4 = e2 * e2, e8 = e4 * e4, e16 = e8 * e8;
    return e + e2 + e4 + e8 + e16;
}

// scaled-domain: arg = -0.125*log2(e)*d2 (<=0); K = t+t^2+t^4+t^8+t^16
__device__ __forceinline__ float multi_gauss2(float arg) {
    float e  = __builtin_amdgcn_exp2f(fminf(arg, 0.f));
    float e2 = e * e, e4 = e2 * e2, e8 = e4 * e4, e16 = e8 * e8;
    return ((e + e2) + (e4 + e8)) + e16;
}

__device__ __forceinline__ unsigned short f2bf(float x) {
    union { float f; unsigned u; } c; c.f = x;
    unsigned r = c.u + 0x7FFFu + ((c.u >> 16) & 1u);   // RNE
    return (unsigned short)(r >> 16);
}
__device__ __forceinline__ float bf2f(unsigned short h) {
    union { float f; unsigned u; } c; c.u = ((unsigned)h) << 16; return c.f;
}

__device__ __forceinline__ float wred(float x) {
    for (int o = 32; o; o >>= 1) x += __shfl_down(x, o, 64);
    return x;
}

// ---------------------------------------------------------------------------
// Kernel 1: prep — fp32 -> bf16 rows (zero-padded to 64 feats) + fp32 ssq;
// also zeros the 3000-float output. 16 threads/row, float4 each.
// ---------------------------------------------------------------------------
__global__ __launch_bounds__(256) void prep(
    const float* __restrict__ sup, const float* __restrict__ qry,
    unsigned short* __restrict__ whi, float* __restrict__ wssq,
    float* __restrict__ out)
{
    int u = blockIdx.x * 256 + threadIdx.x;
    if (u < NOUT) out[u] = 0.f;

    int row = u >> 4;
    int c = (u & 15) * 4;

    const float* src = nullptr;
    if (row < SUPROWS) {
        int i = row & 63, t6 = row >> 6;
        int s = t6 % NS, bg = t6 / NS;
        int g = bg & 3, b = bg >> 2;
        if (i < NF) src = sup + ((size_t)(((b * NS + s) * NG + g) * NF + i)) * CDIM + c;
    } else {
        int r2 = row - SUPROWS;
        int j = r2 & 63, t6 = r2 >> 6;
        int g = t6 & 3, v = (t6 >> 2) % NQ, b = t6 / (NQ * NG);
        if (j < NF) src = qry + ((size_t)(((b * NQ + v) * NG + g) * NF + j)) * CDIM + c;
    }
    float4 x = make_float4(0.f, 0.f, 0.f, 0.f);
    if (src) x = *(const float4*)src;
    ushort4 h4;
    h4.x = f2bf(x.x); h4.y = f2bf(x.y); h4.z = f2bf(x.z); h4.w = f2bf(x.w);
    ((ushort4*)whi)[u] = h4;

    float v2 = x.x * x.x + x.y * x.y + x.z * x.z + x.w * x.w;
    v2 += __shfl_down(v2, 8, 64);
    v2 += __shfl_down(v2, 4, 64);
    v2 += __shfl_down(v2, 2, 64);
    v2 += __shfl_down(v2, 1, 64);
    if ((u & 15) == 0) wssq[row] = v2;
}

// ---------------------------------------------------------------------------
// Kernel 2 (fused): blocks [0, 4800) = cross+qq per (b,v,g,half);
// blocks [4800, 4960) = ss quadratic forms per (b,g,s) via double MFMA.
// Both only atomically add into out (zeroed by prep).
// ---------------------------------------------------------------------------
__global__ __launch_bounds__(256, 5) void mmd_main(
    const unsigned short* __restrict__ whi, const float* __restrict__ wssq,
    const float* __restrict__ beta, const float* __restrict__ gamma,
    float* __restrict__ out)
{
    __shared__ __align__(16) union {
        struct {
            float sbeta[NS][64], sgam[NS][64];
            float ssq[384];
            float red_sq[NS], red_qq[NS];
        } c;
        struct {
            unsigned short Kt[64][72];   // bf16 Kss, row stride 72 (144B, breaks b128 conflicts)
            unsigned short Bt[96][72];   // bf16 beta^T: [v][j], j contiguous for B-frag reads
            float red_s[96];
        } f;
    } sm;

    int blk = blockIdx.x;
    int t = threadIdx.x;
    int w = t >> 6, lane = t & 63, lrow = lane & 31, lhalf = lane >> 5;
    const bf16x8* W = (const bf16x8*)whi;

    if (blk < NCROSS) {
        // ================= cross + qq path (round-4 body) =================
        int h = blk & 1;
        int g = (blk >> 1) & 3;
        int v = (blk >> 3) % NQ;
        int b = blk / (NQ * NG * 2);
        int qc = h * 32;

        int srow0 = (b * NG + g) * (NS * 64);
        int qrow0 = SUPROWS + ((b * NQ + v) * NG + g) * 64;

        for (int u = t; u < 384; u += 256)
            sm.c.ssq[u] = (u < 320) ? wssq[srow0 + u] : wssq[qrow0 + (u - 320)];
        for (int u = t; u < NS * 64; u += 256) {
            int s = u >> 6, i = u & 63;
            float bvv = 0.f, gvv = 0.f;
            if (i < NF) {
                size_t base = (size_t)(((b * NQ + v) * NS + s) * NG + g) * NF + i;
                bvv = beta[base]; gvv = gamma[base];
            }
            sm.c.sbeta[s][i] = bvv; sm.c.sgam[s][i] = gvv;
        }
        if (t < NS) { sm.c.red_sq[t] = 0.f; sm.c.red_qq[t] = 0.f; }

        f32x16 acc[3];
#pragma unroll
        for (int mi = 0; mi < 3; ++mi)
#pragma unroll
            for (int q = 0; q < 16; ++q) acc[mi][q] = 0.f;

        int a2row = (w < 2) ? (srow0 + (8 + w) * 32 + lrow)
                            : (qrow0 + (w - 2) * 32 + lrow);
#pragma unroll
        for (int kc = 0; kc < 4; ++kc) {
            int ko = kc * 2 + lhalf;
            bf16x8 bh = W[(qrow0 + qc + lrow) * 8 + ko];
            bf16x8 a0 = W[(srow0 + w * 32 + lrow) * 8 + ko];
            bf16x8 a1 = W[(srow0 + (w + 4) * 32 + lrow) * 8 + ko];
            bf16x8 a2 = W[a2row * 8 + ko];
            acc[0] = __builtin_amdgcn_mfma_f32_32x32x16_bf16(a0, bh, acc[0], 0, 0, 0);
            acc[1] = __builtin_amdgcn_mfma_f32_32x32x16_bf16(a1, bh, acc[1], 0, 0, 0);
            acc[2] = __builtin_amdgcn_mfma_f32_32x32x16_bf16(a2, bh, acc[2], 0, 0, 0);
        }
        __syncthreads();

        const float c2  = -0.18033688f;   // -0.125 * log2(e)
        const float k2c =  0.36067376f;   // -2 * c2
        float qsq = sm.c.ssq[320 + qc + lrow];
        float c2q = c2 * qsq;

#pragma unroll
        for (int mi = 0; mi < 3; ++mi) {
            int mt = (mi < 2) ? (w + 4 * mi) : ((w < 2) ? (8 + w) : -1);
            if (mt >= 0) {                 // cross tile: s = mt>>1
                int s = mt >> 1;
                int ioff = (mt & 1) * 32;
                float tsum = 0.f;
#pragma unroll
                for (int grp = 0; grp < 4; ++grp) {
                    int rbase = grp * 8 + 4 * lhalf;
                    float4 sqv = *(const float4*)&sm.c.ssq[mt * 32 + rbase];
                    float4 bvv = *(const float4*)&sm.c.sbeta[s][ioff + rbase];
#pragma unroll
                    for (int q = 0; q < 4; ++q) {
                        float sq = (q == 0) ? sqv.x : (q == 1) ? sqv.y : (q == 2) ? sqv.z : sqv.w;
                        float bv = (q == 0) ? bvv.x : (q == 1) ? bvv.y : (q == 2) ? bvv.z : bvv.w;
                        float arg = fmaf(k2c, acc[mi][grp * 4 + q], fmaf(c2, sq, c2q));
                        tsum = fmaf(bv, multi_gauss2(arg), tsum);
                    }
                }
                tsum *= sm.c.sgam[s][qc + lrow];
                tsum = wred(tsum);
                if (lane == 0) atomicAdd(&sm.c.red_sq[s], tsum);
            } else {                       // qq tile
                int qoff = (w - 2) * 32;
                float qs[NS] = {0.f, 0.f, 0.f, 0.f, 0.f};
#pragma unroll
                for (int grp = 0; grp < 4; ++grp) {
                    int rbase = grp * 8 + 4 * lhalf;
                    float4 sqv = *(const float4*)&sm.c.ssq[320 + qoff + rbase];
                    float kvv[4];
#pragma unroll
                    for (int q = 0; q < 4; ++q) {
                        float sq = (q == 0) ? sqv.x : (q == 1) ? sqv.y : (q == 2) ? sqv.z : sqv.w;
                        int row = qoff + rbase + q;
                        float arg = fmaf(k2c, acc[mi][grp * 4 + q], fmaf(c2, sq, c2q));
                        kvv[q] = (row == qc + lrow) ? 5.0f : multi_gauss2(arg);
                    }
#pragma unroll
                    for (int s = 0; s < NS; ++s) {
                        float4 gi = *(const float4*)&sm.c.sgam[s][qoff + rbase];
                        qs[s] = fmaf(gi.x, kvv[0], qs[s]);
                        qs[s] = fmaf(gi.y, kvv[1], qs[s]);
                        qs[s] = fmaf(gi.z, kvv[2], qs[s]);
                        qs[s] = fmaf(gi.w, kvv[3], qs[s]);
                    }
                }
#pragma unroll
                for (int s = 0; s < NS; ++s) {
                    float r = wred(qs[s] * sm.c.sgam[s][qc + lrow]);
                    if (lane == 0) atomicAdd(&sm.c.red_qq[s], r);
                }
            }
        }
        __syncthreads();
        if (t < NS)
            atomicAdd(&out[((size_t)b * NQ + v) * NS + t],
                      0.25f * (sm.c.red_qq[t] - 2.f * sm.c.red_sq[t]));
    } else {
        // ================= ss quadratic-forms path =================
        int k = blk - NCROSS;
        int s = k % NS;
        int bg = k / NS;
        int g = bg & 3, b = bg >> 2;
        int row0 = (b * NG + g) * (NS * 64) + s * 64;

        // stage Bt[v][j] = bf16(beta[b,v,s,g,j]), zero-padded to 96x64
        for (int u = t; u < 96 * 64; u += 256) {
            int v = u >> 6, j = u & 63;
            unsigned short val = 0;
            if (v < NQ && j < NF)
                val = f2bf(beta[(size_t)(((b * NQ + v) * NS + s) * NG + g) * NF + j]);
            sm.f.Bt[v][j] = val;
        }
        if (t < 96) sm.f.red_s[t] = 0.f;

        // Kss 32x32 tile per wave: mt = w>>1, nt = w&1
        int mt = w >> 1, nt = w & 1;
        f32x16 acc;
#pragma unroll
        for (int q = 0; q < 16; ++q) acc[q] = 0.f;
#pragma unroll
        for (int kc = 0; kc < 4; ++kc) {
            int ko = kc * 2 + lhalf;
            bf16x8 a  = W[(row0 + mt * 32 + lrow) * 8 + ko];
            bf16x8 bf = W[(row0 + nt * 32 + lrow) * 8 + ko];
            acc = __builtin_amdgcn_mfma_f32_32x32x16_bf16(a, bf, acc, 0, 0, 0);
        }
        int cj = nt * 32 + lrow;
        float sqj = wssq[row0 + cj];
#pragma unroll
        for (int reg = 0; reg < 16; ++reg) {
            int ri = mt * 32 + (reg & 3) + 8 * (reg >> 2) + 4 * lhalf;
            float kv = (ri == cj) ? 5.0f
                     : multi_gauss(wssq[row0 + ri] + sqj - 2.f * acc[reg]);
            sm.f.Kt[ri][cj] = f2bf(kv);
        }
        __syncthreads();   // Kt + Bt + red_s ready

        // Y = Kt . Bt^T : tiles T in [0,6): mt2 = T/3, nt2 = T%3
#pragma unroll
        for (int pass = 0; pass < 2; ++pass) {
            int T = (pass == 0) ? w : ((w < 2) ? 4 + w : -1);
            if (T < 0) continue;
            int mt2 = T / 3, nt2 = T % 3;
            f32x16 yacc;
#pragma unroll
            for (int q = 0; q < 16; ++q) yacc[q] = 0.f;
#pragma unroll
            for (int kc = 0; kc < 4; ++kc) {
                int koff = kc * 16 + lhalf * 8;
                bf16x8 af = *(const bf16x8*)&sm.f.Kt[mt2 * 32 + lrow][koff];
                bf16x8 bf = *(const bf16x8*)&sm.f.Bt[nt2 * 32 + lrow][koff];
                yacc = __builtin_amdgcn_mfma_f32_32x32x16_bf16(af, bf, yacc, 0, 0, 0);
            }
            int v = nt2 * 32 + lrow;
            float p = 0.f;
#pragma unroll
            for (int reg = 0; reg < 16; ++reg) {
                int i = mt2 * 32 + (reg & 3) + 8 * (reg >> 2) + 4 * lhalf;
                p = fmaf(yacc[reg], bf2f(sm.f.Bt[v][i]), p);
            }
            p += __shfl_xor(p, 32, 64);
            if (lane < 32) atomicAdd(&sm.f.red_s[v], p);
        }
        __syncthreads();
        if (t < NQ)
            atomicAdd(&out[((size_t)b * NQ + t) * NS + s], 0.25f * sm.f.red_s[t]);
    }
}

extern "C" void kernel_launch(void* const* d_in, const int* in_sizes, int n_in,
                              void* d_out, int out_size, void* d_ws, size_t ws_size,
                              hipStream_t stream) {
    const float* sup   = (const float*)d_in[0];
    const float* qry   = (const float*)d_in[1];
    const float* beta  = (const float*)d_in[2];
    const float* gamma = (const float*)d_in[3];
    float* out = (float*)d_out;

    unsigned short* whi = (unsigned short*)d_ws;                 // 21 MB
    float* wssq = (float*)(whi + (size_t)TOTROWS * 64);          // 0.66 MB

    prep<<<(TOTROWS * 16) / 256, 256, 0, stream>>>(sup, qry, whi, wssq, out);
    mmd_main<<<NCROSS + NFORM, 256, 0, stream>>>(whi, wssq, beta, gamma, out);
}